// Round 8
// baseline (324.113 us; speedup 1.0000x reference)
//
#include <hip/hip_runtime.h>
#include <hip/hip_bf16.h>
#include <math.h>

#define N_NODES 8192
#define IN_DIM  512
#define H_DIM   128
#define KC      1024              // K-chunk per k-block in k_A
#define NKB     (N_NODES / KC)    // 8
#define BMR     128               // adj rows per k_A block (8 waves x 16)

typedef __attribute__((ext_vector_type(8))) short bf16x8;
typedef __attribute__((ext_vector_type(4))) float f32x4;

__device__ __forceinline__ float lrelu(float x) { return fmaxf(x, 0.2f * x); }

// monotonic float<->uint mapping for atomicMax on floats (all finite maps > 0)
__device__ __forceinline__ unsigned int f2mono(float x) {
    unsigned int b = __float_as_uint(x);
    return (b & 0x80000000u) ? ~b : (b | 0x80000000u);
}
__device__ __forceinline__ float mono2f(unsigned int u) {
    unsigned int b = (u & 0x80000000u) ? (u ^ 0x80000000u) : ~u;
    return __uint_as_float(b);
}

__device__ __forceinline__ short f2bf(float x) {
    union { __hip_bfloat16 h; short s; } cv;
    cv.h = __float2bfloat16(x);
    return cv.s;
}

// Wh = h @ W_w^T + W_b (f32) ; also WhT = bf16 transpose [H_DIM][N_NODES]
__global__ __launch_bounds__(256) void k_wh(const float* __restrict__ h,
                                            const float* __restrict__ Ww,
                                            const float* __restrict__ Wb,
                                            float* __restrict__ Wh,
                                            __hip_bfloat16* __restrict__ WhT) {
    const int BM = 32, BK = 64;
    __shared__ float hT[BK][BM + 4];
    __shared__ float wT[BK][H_DIM + 4];
    const int tid = threadIdx.x;
    const int w = tid >> 6, lane = tid & 63;
    const int trm = tid >> 5, tcm = tid & 31;
    const int row0 = blockIdx.x * BM;

    float acc[4][4] = {};
    for (int k0 = 0; k0 < IN_DIM; k0 += BK) {
        __syncthreads();
        #pragma unroll
        for (int p = 0; p < 8; ++p) {
            int r = 4 * p + w;
            hT[lane][r] = h[(size_t)(row0 + r) * IN_DIM + k0 + lane];
        }
        #pragma unroll
        for (int p = 0; p < 32; ++p) {
            int c = 4 * p + w;
            wT[lane][c] = Ww[(size_t)c * IN_DIM + k0 + lane];
        }
        __syncthreads();
        #pragma unroll 8
        for (int kk = 0; kk < BK; ++kk) {
            f32x4 a4 = *(const f32x4*)&hT[kk][4 * trm];
            f32x4 b4 = *(const f32x4*)&wT[kk][4 * tcm];
            #pragma unroll
            for (int i = 0; i < 4; ++i)
                #pragma unroll
                for (int j = 0; j < 4; ++j)
                    acc[i][j] = fmaf(a4[i], b4[j], acc[i][j]);
        }
    }
    f32x4 wb4 = *(const f32x4*)&Wb[4 * tcm];
    #pragma unroll
    for (int i = 0; i < 4; ++i) {
        int row = row0 + 4 * trm + i;
        f32x4 v;
        #pragma unroll
        for (int jj = 0; jj < 4; ++jj) v[jj] = acc[i][jj] + wb4[jj];
        *(f32x4*)&Wh[(size_t)row * H_DIM + 4 * tcm] = v;
        #pragma unroll
        for (int jj = 0; jj < 4; ++jj)
            WhT[(size_t)(4 * tcm + jj) * N_NODES + row] = __float2bfloat16(v[jj]);
    }
}

// s_i = Wh_i . a ; global max(s) via mapped atomicMax
__global__ __launch_bounds__(256) void k_s(const float* __restrict__ Wh,
                                           const float* __restrict__ a,
                                           float* __restrict__ s,
                                           unsigned int* __restrict__ smax) {
    const int w = threadIdx.x >> 6, lane = threadIdx.x & 63;
    const int row = blockIdx.x * 4 + w;
    float2 av = *(const float2*)&a[lane * 2];
    float2 wh = *(const float2*)&Wh[(size_t)row * H_DIM + lane * 2];
    float v = wh.x * av.x + wh.y * av.y;
    #pragma unroll
    for (int off = 32; off > 0; off >>= 1) v += __shfl_down(v, off);
    __shared__ float bmax[4];
    if (lane == 0) { s[row] = v; bmax[w] = v; }
    __syncthreads();
    if (threadIdx.x == 0) {
        float m = fmaxf(fmaxf(bmax[0], bmax[1]), fmaxf(bmax[2], bmax[3]));
        atomicMax(smax, f2mono(m));
    }
}

// Streaming MFMA pass over adj. Round-8 decomposition: each of 8 waves owns 16
// adj rows x ALL 128 H cols (acc[8] fragments) -> the exp/cvt afrag is computed
// ONCE per (row, j) (round-7 duplicated it across col-half waves; VALU was the
// floor). T14 async-STAGE: next 64-col tile's loads issue right after the
// LDS-publish barrier and are vmcnt-waited only at the next mask-write, so HBM
// latency hides under exp+16 MFMA consume. Mask tile 128x64B, XOR-swizzled.
__global__ __launch_bounds__(512) void k_A(const float* __restrict__ adj,
                                           const __hip_bfloat16* __restrict__ WhT,
                                           const float* __restrict__ s,
                                           const unsigned int* __restrict__ smaxp,
                                           float* __restrict__ denom,
                                           float* __restrict__ y,
                                           unsigned long long* __restrict__ bmask,
                                           int write_mask) {
    __shared__ unsigned char msk[BMR * 64];   // 8KB byte-mask tile, slot-swizzled
    const int NTW = N_NODES / 64;  // bmask words per row
    const int tid  = threadIdx.x;
    const int lane = tid & 63;
    const int w    = tid >> 6;     // wave = row-group of 16
    const int r16  = lane & 15;
    const int kq   = lane >> 4;    // k-quarter: k = kq*8 + e
    const int row0 = blockIdx.x * BMR;
    const int j0base = blockIdx.y * KC;
    const int rowA = row0 + w * 16 + r16;

    const float smax = mono2f(*smaxp);
    const float si = s[rowA];
    const float mi = lrelu(si + smax);

    f32x4 acc[8] = {{0.f,0.f,0.f,0.f},{0.f,0.f,0.f,0.f},{0.f,0.f,0.f,0.f},{0.f,0.f,0.f,0.f},
                    {0.f,0.f,0.f,0.f},{0.f,0.f,0.f,0.f},{0.f,0.f,0.f,0.f},{0.f,0.f,0.f,0.f}};
    float dsum = 0.f;

    const float* sp = s + j0base + kq * 8;
    const __hip_bfloat16* bp = WhT + (size_t)r16 * N_NODES + j0base + kq * 8;

    // staging geometry: tile = BMR rows x 64 cols; 4 rounds x 512 threads of
    // 16B segments. round p, thread t: seg = p*512+t; row = seg>>4; col4 = (seg&15)*4.
    int sRow[4], sCol[4];
    #pragma unroll
    for (int p = 0; p < 4; ++p) {
        int seg = p * 512 + tid;
        sRow[p] = seg >> 4;
        sCol[p] = (seg & 15) * 4;
    }

    const int NBIG = KC / 64;  // 16 big-steps of 64 cols

    f32x4 areg[4];
    #pragma unroll
    for (int p = 0; p < 4; ++p)
        areg[p] = __builtin_nontemporal_load(
            (const f32x4*)(adj + (size_t)(row0 + sRow[p]) * N_NODES + j0base + sCol[p]));

    unsigned long long pend = 0ull;

    for (int bs = 0; bs < NBIG; ++bs) {
        __syncthreads();   // previous tile fully consumed by all waves
        // publish masks (vmcnt wait on areg happens here)
        #pragma unroll
        for (int p = 0; p < 4; ++p) {
            f32x4 a4 = areg[p];
            unsigned int mwd = 0u;
            mwd |= (a4[0] != 0.f) ? 0x00000001u : 0u;
            mwd |= (a4[1] != 0.f) ? 0x00000100u : 0u;
            mwd |= (a4[2] != 0.f) ? 0x00010000u : 0u;
            mwd |= (a4[3] != 0.f) ? 0x01000000u : 0u;
            int r = sRow[p], c = sCol[p];
            int slot = (c >> 3) ^ (r & 7);
            *(unsigned int*)&msk[r * 64 + (slot << 3) + (c & 7)] = mwd;
        }
        __syncthreads();   // tile visible
        // T14: issue next tile's loads now; waited at next publish (covered by consume)
        if (bs + 1 < NBIG) {
            const int j1 = j0base + (bs + 1) * 64;
            #pragma unroll
            for (int p = 0; p < 4; ++p)
                areg[p] = __builtin_nontemporal_load(
                    (const f32x4*)(adj + (size_t)(row0 + sRow[p]) * N_NODES + j1 + sCol[p]));
        }

        // consume: 2 substeps of 32 cols
        #pragma unroll
        for (int sub = 0; sub < 2; ++sub) {
            const int ts = bs * 2 + sub;          // global 32-col step in [0,32)
            const int rT = w * 16 + r16;
            const int slotR = (sub * 4 + kq) ^ (r16 & 7);
            unsigned long long m8 =
                *(const unsigned long long*)&msk[rT * 64 + (slotR << 3)];

            f32x4 sc0 = *(const f32x4*)(sp + ts * 32);
            f32x4 sc1 = *(const f32x4*)(sp + ts * 32 + 4);
            float sv[8] = {sc0[0], sc0[1], sc0[2], sc0[3], sc1[0], sc1[1], sc1[2], sc1[3]};
            bf16x8 afrag;
            unsigned int bits = 0u;
            #pragma unroll
            for (int e = 0; e < 8; ++e) {
                bool nb = ((m8 >> (8 * e)) & 0xffull) != 0ull;
                float ex = nb ? __expf(lrelu(si + sv[e]) - mi) : 0.f;
                dsum += ex;
                bits |= nb ? (1u << e) : 0u;
                afrag[e] = f2bf(ex);
            }
            // 8 MFMA fragments cover all 128 H cols; two halves limit live bc regs
            #pragma unroll
            for (int half = 0; half < 2; ++half) {
                bf16x8 bc[4];
                #pragma unroll
                for (int f = 0; f < 4; ++f)
                    bc[f] = *(const bf16x8*)(bp + (size_t)ts * 32 +
                                             (size_t)(half * 4 + f) * 16 * N_NODES);
                #pragma unroll
                for (int f = 0; f < 4; ++f)
                    acc[half * 4 + f] =
                        __builtin_amdgcn_mfma_f32_16x16x32_bf16(afrag, bc[f], acc[half * 4 + f], 0, 0, 0);
            }
            // bitmask: 32 bits/step, pair 2 steps -> one 64-bit word per row
            if (write_mask) {
                unsigned long long w32 = (unsigned long long)bits << (8 * kq);
                if ((ts & 1) == 0) {
                    pend = w32;
                } else {
                    unsigned long long full = pend | (w32 << 32);
                    full |= __shfl_xor(full, 16);
                    full |= __shfl_xor(full, 32);
                    if (lane < 16)
                        bmask[(size_t)(row0 + w * 16 + lane) * NTW + ((j0base + ts * 32) >> 6)] = full;
                }
            }
        }
    }

    // denom partial: reduce over kq lanes (same r16)
    {
        float v = dsum;
        v += __shfl_xor(v, 16);
        v += __shfl_xor(v, 32);
        if (lane < 16) atomicAdd(&denom[row0 + w * 16 + lane], v);
    }
    // y partial: D layout col = f*16 + (lane&15), row = (lane>>4)*4 + reg
    #pragma unroll
    for (int f = 0; f < 8; ++f)
        #pragma unroll
        for (int i = 0; i < 4; ++i) {
            int rr = row0 + w * 16 + kq * 4 + i;
            int cc = f * 16 + r16;
            atomicAdd(&y[(size_t)rr * H_DIM + cc], acc[f][i]);
        }
}

// alpha_ij = ex_ij / denom_i ; reads 8MB bitmask (or adj fallback), writes 268MB nt
__global__ __launch_bounds__(256) void k_B(const unsigned long long* __restrict__ bmask,
                                           const float* __restrict__ adj,
                                           const float* __restrict__ s,
                                           const float* __restrict__ denom,
                                           const unsigned int* __restrict__ smaxp,
                                           float* __restrict__ alpha,
                                           int use_mask) {
    const int NSTEP = N_NODES / 256;  // 32 (each wave covers 256 cols/step as float4)
    const int w = threadIdx.x >> 6, lane = threadIdx.x & 63;
    const int row = blockIdx.x * 4 + w;
    const float smax = mono2f(*smaxp);
    const float si = s[row];
    const float mi = lrelu(si + smax);
    const float d = denom[row];
    const float rd = d > 0.f ? 1.f / d : 0.f;
    float* arow = alpha + (size_t)row * N_NODES;
    if (use_mask) {
        const unsigned long long* mrow = bmask + (size_t)row * (N_NODES / 64);
        #pragma unroll 4
        for (int t = 0; t < NSTEP; ++t) {
            int col = t * 256 + lane * 4;
            unsigned long long mb = mrow[t * 4 + (lane >> 4)];
            int sh = (lane & 15) * 4;
            f32x4 sj = *(const f32x4*)&s[col];
            f32x4 o;
            o[0] = ((mb >> (sh + 0)) & 1ull) ? __expf(lrelu(si + sj[0]) - mi) * rd : 0.f;
            o[1] = ((mb >> (sh + 1)) & 1ull) ? __expf(lrelu(si + sj[1]) - mi) * rd : 0.f;
            o[2] = ((mb >> (sh + 2)) & 1ull) ? __expf(lrelu(si + sj[2]) - mi) * rd : 0.f;
            o[3] = ((mb >> (sh + 3)) & 1ull) ? __expf(lrelu(si + sj[3]) - mi) * rd : 0.f;
            __builtin_nontemporal_store(o, (f32x4*)&arow[col]);
        }
    } else {
        const float* adjrow = adj + (size_t)row * N_NODES;
        #pragma unroll 4
        for (int t = 0; t < NSTEP; ++t) {
            int col = t * 256 + lane * 4;
            f32x4 a4 = __builtin_nontemporal_load((const f32x4*)&adjrow[col]);
            f32x4 sj = *(const f32x4*)&s[col];
            f32x4 o;
            o[0] = (a4[0] != 0.f) ? __expf(lrelu(si + sj[0]) - mi) * rd : 0.f;
            o[1] = (a4[1] != 0.f) ? __expf(lrelu(si + sj[1]) - mi) * rd : 0.f;
            o[2] = (a4[2] != 0.f) ? __expf(lrelu(si + sj[2]) - mi) * rd : 0.f;
            o[3] = (a4[3] != 0.f) ? __expf(lrelu(si + sj[3]) - mi) * rd : 0.f;
            __builtin_nontemporal_store(o, (f32x4*)&arow[col]);
        }
    }
}

// z = sigmoid(y/denom)
__global__ __launch_bounds__(256) void k_z(const float* __restrict__ y,
                                           const float* __restrict__ denom,
                                           float* __restrict__ z) {
    int i = blockIdx.x * 256 + threadIdx.x;
    int row = i >> 7;
    float d = denom[row];
    float rd = d > 0.f ? 1.f / d : 0.f;
    float v = y[i] * rd;
    z[i] = 1.f / (1.f + __expf(-v));
}

extern "C" void kernel_launch(void* const* d_in, const int* in_sizes, int n_in,
                              void* d_out, int out_size, void* d_ws, size_t ws_size,
                              hipStream_t stream) {
    const float* h   = (const float*)d_in[0];
    const float* adj = (const float*)d_in[1];
    const float* Ww  = (const float*)d_in[2];
    const float* Wb  = (const float*)d_in[3];
    const float* a   = (const float*)d_in[4];

    float* z     = (float*)d_out;
    float* alpha = z + (size_t)N_NODES * H_DIM;

    char* ws = (char*)d_ws;
    float* y     = (float*)ws;  ws += sizeof(float) * (size_t)N_NODES * H_DIM;   // 4MB (zeroed)
    float* denom = (float*)ws;  ws += sizeof(float) * N_NODES;                   // 32KB (zeroed)
    unsigned int* smax = (unsigned int*)ws;  ws += 256;                          // (zeroed)
    size_t zero_bytes = (size_t)(ws - (char*)d_ws);
    float* Wh    = (float*)ws;  ws += sizeof(float) * (size_t)N_NODES * H_DIM;   // 4MB
    __hip_bfloat16* WhT = (__hip_bfloat16*)ws;
    ws += sizeof(__hip_bfloat16) * (size_t)N_NODES * H_DIM;                      // 2MB
    float* s     = (float*)ws;  ws += sizeof(float) * N_NODES;                   // 32KB
    unsigned long long* bmask = (unsigned long long*)ws;
    size_t base_need  = (size_t)(ws - (char*)d_ws);
    size_t mask_bytes = (size_t)N_NODES * (N_NODES / 64) * sizeof(unsigned long long);
    int use_mask = (ws_size >= base_need + mask_bytes) ? 1 : 0;

    (void)hipMemsetAsync(d_ws, 0, zero_bytes, stream);
    hipLaunchKernelGGL(k_wh, dim3(N_NODES / 32), dim3(256), 0, stream, h, Ww, Wb, Wh, WhT);
    hipLaunchKernelGGL(k_s,  dim3(N_NODES / 4),  dim3(256), 0, stream, Wh, a, s, smax);
    hipLaunchKernelGGL(k_A,  dim3(N_NODES / BMR, NKB), dim3(512), 0, stream,
                       adj, WhT, s, smax, denom, y, bmask, use_mask);
    hipLaunchKernelGGL(k_B,  dim3(N_NODES / 4),  dim3(256), 0, stream,
                       bmask, adj, s, denom, smax, alpha, use_mask);
    hipLaunchKernelGGL(k_z,  dim3((N_NODES * H_DIM) / 256), dim3(256), 0, stream,
                       y, denom, z);
}

// Round 9
// 304.785 us; speedup vs baseline: 1.0634x; 1.0634x over previous
//
#include <hip/hip_runtime.h>
#include <hip/hip_bf16.h>
#include <math.h>

#define N_NODES 8192
#define IN_DIM  512
#define H_DIM   128
#define KC      512               // K-chunk per k-block in k_A
#define NKB     (N_NODES / KC)    // 16
#define BMR     64                // adj rows per k_A block (4 waves x 16)

typedef __attribute__((ext_vector_type(8))) short bf16x8;
typedef __attribute__((ext_vector_type(4))) float f32x4;

__device__ __forceinline__ float lrelu(float x) { return fmaxf(x, 0.2f * x); }

// monotonic float<->uint mapping for atomicMax on floats (all finite maps > 0)
__device__ __forceinline__ unsigned int f2mono(float x) {
    unsigned int b = __float_as_uint(x);
    return (b & 0x80000000u) ? ~b : (b | 0x80000000u);
}
__device__ __forceinline__ float mono2f(unsigned int u) {
    unsigned int b = (u & 0x80000000u) ? (u ^ 0x80000000u) : ~u;
    return __uint_as_float(b);
}

__device__ __forceinline__ short f2bf(float x) {
    union { __hip_bfloat16 h; short s; } cv;
    cv.h = __float2bfloat16(x);
    return cv.s;
}

// Wh = h @ W_w^T + W_b (f32) ; also WhT = bf16 transpose [H_DIM][N_NODES]
__global__ __launch_bounds__(256) void k_wh(const float* __restrict__ h,
                                            const float* __restrict__ Ww,
                                            const float* __restrict__ Wb,
                                            float* __restrict__ Wh,
                                            __hip_bfloat16* __restrict__ WhT) {
    const int BM = 32, BK = 64;
    __shared__ float hT[BK][BM + 4];
    __shared__ float wT[BK][H_DIM + 4];
    const int tid = threadIdx.x;
    const int w = tid >> 6, lane = tid & 63;
    const int trm = tid >> 5, tcm = tid & 31;
    const int row0 = blockIdx.x * BM;

    float acc[4][4] = {};
    for (int k0 = 0; k0 < IN_DIM; k0 += BK) {
        __syncthreads();
        #pragma unroll
        for (int p = 0; p < 8; ++p) {
            int r = 4 * p + w;
            hT[lane][r] = h[(size_t)(row0 + r) * IN_DIM + k0 + lane];
        }
        #pragma unroll
        for (int p = 0; p < 32; ++p) {
            int c = 4 * p + w;
            wT[lane][c] = Ww[(size_t)c * IN_DIM + k0 + lane];
        }
        __syncthreads();
        #pragma unroll 8
        for (int kk = 0; kk < BK; ++kk) {
            f32x4 a4 = *(const f32x4*)&hT[kk][4 * trm];
            f32x4 b4 = *(const f32x4*)&wT[kk][4 * tcm];
            #pragma unroll
            for (int i = 0; i < 4; ++i)
                #pragma unroll
                for (int j = 0; j < 4; ++j)
                    acc[i][j] = fmaf(a4[i], b4[j], acc[i][j]);
        }
    }
    f32x4 wb4 = *(const f32x4*)&Wb[4 * tcm];
    #pragma unroll
    for (int i = 0; i < 4; ++i) {
        int row = row0 + 4 * trm + i;
        f32x4 v;
        #pragma unroll
        for (int jj = 0; jj < 4; ++jj) v[jj] = acc[i][jj] + wb4[jj];
        *(f32x4*)&Wh[(size_t)row * H_DIM + 4 * tcm] = v;
        #pragma unroll
        for (int jj = 0; jj < 4; ++jj)
            WhT[(size_t)(4 * tcm + jj) * N_NODES + row] = __float2bfloat16(v[jj]);
    }
}

// s_i = Wh_i . a ; global max(s) via mapped atomicMax
__global__ __launch_bounds__(256) void k_s(const float* __restrict__ Wh,
                                           const float* __restrict__ a,
                                           float* __restrict__ s,
                                           unsigned int* __restrict__ smax) {
    const int w = threadIdx.x >> 6, lane = threadIdx.x & 63;
    const int row = blockIdx.x * 4 + w;
    float2 av = *(const float2*)&a[lane * 2];
    float2 wh = *(const float2*)&Wh[(size_t)row * H_DIM + lane * 2];
    float v = wh.x * av.x + wh.y * av.y;
    #pragma unroll
    for (int off = 32; off > 0; off >>= 1) v += __shfl_down(v, off);
    __shared__ float bmax[4];
    if (lane == 0) { s[row] = v; bmax[w] = v; }
    __syncthreads();
    if (threadIdx.x == 0) {
        float m = fmaxf(fmaxf(bmax[0], bmax[1]), fmaxf(bmax[2], bmax[3]));
        atomicMax(smax, f2mono(m));
    }
}

// Streaming MFMA pass over adj. Round-9: keep round-8's dedup decomposition
// (each wave owns 16 rows x ALL 128 H cols; exp once per (i,j)) but restore TLP:
// 256-thread blocks (4 waves), BMR=64, KC=512 -> grid (128,16)=2048 blocks =
// up to 8 blocks/CU (round-8's 512x512t grid was 2 blocks/CU; Occupancy 22.7%
// and latency-bound at 205us). T14 stage ordering kept: next tile's loads issue
// right after the publish barrier and drain at the NEXT iteration's first
// barrier, so consume (exp + 16 MFMA) covers HBM latency.
__global__ __launch_bounds__(256) void k_A(const float* __restrict__ adj,
                                           const __hip_bfloat16* __restrict__ WhT,
                                           const float* __restrict__ s,
                                           const unsigned int* __restrict__ smaxp,
                                           float* __restrict__ denom,
                                           float* __restrict__ y,
                                           unsigned long long* __restrict__ bmask,
                                           int write_mask) {
    __shared__ unsigned char msk[BMR * 64];   // 4KB byte-mask tile, slot-swizzled
    const int NTW = N_NODES / 64;  // bmask words per row
    const int tid  = threadIdx.x;
    const int lane = tid & 63;
    const int w    = tid >> 6;     // wave = row-group of 16
    const int r16  = lane & 15;
    const int kq   = lane >> 4;    // k-quarter: k = kq*8 + e
    const int row0 = blockIdx.x * BMR;
    const int j0base = blockIdx.y * KC;
    const int rowA = row0 + w * 16 + r16;

    const float smax = mono2f(*smaxp);
    const float si = s[rowA];
    const float mi = lrelu(si + smax);

    f32x4 acc[8] = {{0.f,0.f,0.f,0.f},{0.f,0.f,0.f,0.f},{0.f,0.f,0.f,0.f},{0.f,0.f,0.f,0.f},
                    {0.f,0.f,0.f,0.f},{0.f,0.f,0.f,0.f},{0.f,0.f,0.f,0.f},{0.f,0.f,0.f,0.f}};
    float dsum = 0.f;

    const float* sp = s + j0base + kq * 8;
    const __hip_bfloat16* bp = WhT + (size_t)r16 * N_NODES + j0base + kq * 8;

    // staging geometry: tile = BMR(64) rows x 64 cols; 4 rounds x 256 threads of
    // 16B segments. round p, thread t: seg = p*256+t; row = seg>>4; col = (seg&15)*4.
    int sRow[4], sCol[4];
    #pragma unroll
    for (int p = 0; p < 4; ++p) {
        int seg = p * 256 + tid;
        sRow[p] = seg >> 4;
        sCol[p] = (seg & 15) * 4;
    }

    const int NBIG = KC / 64;  // 8 big-steps of 64 cols

    f32x4 areg[4];
    #pragma unroll
    for (int p = 0; p < 4; ++p)
        areg[p] = __builtin_nontemporal_load(
            (const f32x4*)(adj + (size_t)(row0 + sRow[p]) * N_NODES + j0base + sCol[p]));

    unsigned long long pend = 0ull;

    for (int bs = 0; bs < NBIG; ++bs) {
        __syncthreads();   // previous tile fully consumed by all waves
        // publish masks (vmcnt wait on areg happens here)
        #pragma unroll
        for (int p = 0; p < 4; ++p) {
            f32x4 a4 = areg[p];
            unsigned int mwd = 0u;
            mwd |= (a4[0] != 0.f) ? 0x00000001u : 0u;
            mwd |= (a4[1] != 0.f) ? 0x00000100u : 0u;
            mwd |= (a4[2] != 0.f) ? 0x00010000u : 0u;
            mwd |= (a4[3] != 0.f) ? 0x01000000u : 0u;
            int r = sRow[p], c = sCol[p];
            int slot = (c >> 3) ^ (r & 7);
            *(unsigned int*)&msk[r * 64 + (slot << 3) + (c & 7)] = mwd;
        }
        __syncthreads();   // tile visible
        // T14: issue next tile's loads now; waited at next publish (covered by consume)
        if (bs + 1 < NBIG) {
            const int j1 = j0base + (bs + 1) * 64;
            #pragma unroll
            for (int p = 0; p < 4; ++p)
                areg[p] = __builtin_nontemporal_load(
                    (const f32x4*)(adj + (size_t)(row0 + sRow[p]) * N_NODES + j1 + sCol[p]));
        }

        // consume: 2 substeps of 32 cols
        #pragma unroll
        for (int sub = 0; sub < 2; ++sub) {
            const int ts = bs * 2 + sub;          // global 32-col step in [0, KC/32)
            const int rT = w * 16 + r16;
            const int slotR = (sub * 4 + kq) ^ (r16 & 7);
            unsigned long long m8 =
                *(const unsigned long long*)&msk[rT * 64 + (slotR << 3)];
            // bytes are exactly 0/1: gather LSBs -> 8-bit neighbor mask
            unsigned int bits =
                (unsigned int)((m8 * 0x0102040810204080ull) >> 56) & 0xffu;

            f32x4 sc0 = *(const f32x4*)(sp + ts * 32);
            f32x4 sc1 = *(const f32x4*)(sp + ts * 32 + 4);
            float sv[8] = {sc0[0], sc0[1], sc0[2], sc0[3], sc1[0], sc1[1], sc1[2], sc1[3]};
            bf16x8 afrag;
            #pragma unroll
            for (int e = 0; e < 8; ++e) {
                bool nb = (bits >> e) & 1u;
                float ex = nb ? __expf(lrelu(si + sv[e]) - mi) : 0.f;
                dsum += ex;
                afrag[e] = f2bf(ex);
            }
            // 8 MFMA fragments cover all 128 H cols; two halves limit live bc regs
            #pragma unroll
            for (int half = 0; half < 2; ++half) {
                bf16x8 bc[4];
                #pragma unroll
                for (int f = 0; f < 4; ++f)
                    bc[f] = *(const bf16x8*)(bp + (size_t)ts * 32 +
                                             (size_t)(half * 4 + f) * 16 * N_NODES);
                #pragma unroll
                for (int f = 0; f < 4; ++f)
                    acc[half * 4 + f] =
                        __builtin_amdgcn_mfma_f32_16x16x32_bf16(afrag, bc[f], acc[half * 4 + f], 0, 0, 0);
            }
            // bitmask: 32 bits/step, pair 2 steps -> one 64-bit word per row
            if (write_mask) {
                unsigned long long w32 = (unsigned long long)bits << (8 * kq);
                if ((ts & 1) == 0) {
                    pend = w32;
                } else {
                    unsigned long long full = pend | (w32 << 32);
                    full |= __shfl_xor(full, 16);
                    full |= __shfl_xor(full, 32);
                    if (lane < 16)
                        bmask[(size_t)(row0 + w * 16 + lane) * NTW + ((j0base + ts * 32) >> 6)] = full;
                }
            }
        }
    }

    // denom partial: reduce over kq lanes (same r16)
    {
        float v = dsum;
        v += __shfl_xor(v, 16);
        v += __shfl_xor(v, 32);
        if (lane < 16) atomicAdd(&denom[row0 + w * 16 + lane], v);
    }
    // y partial: D layout col = f*16 + (lane&15), row = (lane>>4)*4 + reg
    #pragma unroll
    for (int f = 0; f < 8; ++f)
        #pragma unroll
        for (int i = 0; i < 4; ++i) {
            int rr = row0 + w * 16 + kq * 4 + i;
            int cc = f * 16 + r16;
            atomicAdd(&y[(size_t)rr * H_DIM + cc], acc[f][i]);
        }
}

// alpha_ij = ex_ij / denom_i ; reads 8MB bitmask (or adj fallback), writes 268MB nt
__global__ __launch_bounds__(256) void k_B(const unsigned long long* __restrict__ bmask,
                                           const float* __restrict__ adj,
                                           const float* __restrict__ s,
                                           const float* __restrict__ denom,
                                           const unsigned int* __restrict__ smaxp,
                                           float* __restrict__ alpha,
                                           int use_mask) {
    const int NSTEP = N_NODES / 256;  // 32 (each wave covers 256 cols/step as float4)
    const int w = threadIdx.x >> 6, lane = threadIdx.x & 63;
    const int row = blockIdx.x * 4 + w;
    const float smax = mono2f(*smaxp);
    const float si = s[row];
    const float mi = lrelu(si + smax);
    const float d = denom[row];
    const float rd = d > 0.f ? 1.f / d : 0.f;
    float* arow = alpha + (size_t)row * N_NODES;
    if (use_mask) {
        const unsigned long long* mrow = bmask + (size_t)row * (N_NODES / 64);
        #pragma unroll 4
        for (int t = 0; t < NSTEP; ++t) {
            int col = t * 256 + lane * 4;
            unsigned long long mb = mrow[t * 4 + (lane >> 4)];
            int sh = (lane & 15) * 4;
            f32x4 sj = *(const f32x4*)&s[col];
            f32x4 o;
            o[0] = ((mb >> (sh + 0)) & 1ull) ? __expf(lrelu(si + sj[0]) - mi) * rd : 0.f;
            o[1] = ((mb >> (sh + 1)) & 1ull) ? __expf(lrelu(si + sj[1]) - mi) * rd : 0.f;
            o[2] = ((mb >> (sh + 2)) & 1ull) ? __expf(lrelu(si + sj[2]) - mi) * rd : 0.f;
            o[3] = ((mb >> (sh + 3)) & 1ull) ? __expf(lrelu(si + sj[3]) - mi) * rd : 0.f;
            __builtin_nontemporal_store(o, (f32x4*)&arow[col]);
        }
    } else {
        const float* adjrow = adj + (size_t)row * N_NODES;
        #pragma unroll 4
        for (int t = 0; t < NSTEP; ++t) {
            int col = t * 256 + lane * 4;
            f32x4 a4 = __builtin_nontemporal_load((const f32x4*)&adjrow[col]);
            f32x4 sj = *(const f32x4*)&s[col];
            f32x4 o;
            o[0] = (a4[0] != 0.f) ? __expf(lrelu(si + sj[0]) - mi) * rd : 0.f;
            o[1] = (a4[1] != 0.f) ? __expf(lrelu(si + sj[1]) - mi) * rd : 0.f;
            o[2] = (a4[2] != 0.f) ? __expf(lrelu(si + sj[2]) - mi) * rd : 0.f;
            o[3] = (a4[3] != 0.f) ? __expf(lrelu(si + sj[3]) - mi) * rd : 0.f;
            __builtin_nontemporal_store(o, (f32x4*)&arow[col]);
        }
    }
}

// z = sigmoid(y/denom)
__global__ __launch_bounds__(256) void k_z(const float* __restrict__ y,
                                           const float* __restrict__ denom,
                                           float* __restrict__ z) {
    int i = blockIdx.x * 256 + threadIdx.x;
    int row = i >> 7;
    float d = denom[row];
    float rd = d > 0.f ? 1.f / d : 0.f;
    float v = y[i] * rd;
    z[i] = 1.f / (1.f + __expf(-v));
}

extern "C" void kernel_launch(void* const* d_in, const int* in_sizes, int n_in,
                              void* d_out, int out_size, void* d_ws, size_t ws_size,
                              hipStream_t stream) {
    const float* h   = (const float*)d_in[0];
    const float* adj = (const float*)d_in[1];
    const float* Ww  = (const float*)d_in[2];
    const float* Wb  = (const float*)d_in[3];
    const float* a   = (const float*)d_in[4];

    float* z     = (float*)d_out;
    float* alpha = z + (size_t)N_NODES * H_DIM;

    char* ws = (char*)d_ws;
    float* y     = (float*)ws;  ws += sizeof(float) * (size_t)N_NODES * H_DIM;   // 4MB (zeroed)
    float* denom = (float*)ws;  ws += sizeof(float) * N_NODES;                   // 32KB (zeroed)
    unsigned int* smax = (unsigned int*)ws;  ws += 256;                          // (zeroed)
    size_t zero_bytes = (size_t)(ws - (char*)d_ws);
    float* Wh    = (float*)ws;  ws += sizeof(float) * (size_t)N_NODES * H_DIM;   // 4MB
    __hip_bfloat16* WhT = (__hip_bfloat16*)ws;
    ws += sizeof(__hip_bfloat16) * (size_t)N_NODES * H_DIM;                      // 2MB
    float* s     = (float*)ws;  ws += sizeof(float) * N_NODES;                   // 32KB
    unsigned long long* bmask = (unsigned long long*)ws;
    size_t base_need  = (size_t)(ws - (char*)d_ws);
    size_t mask_bytes = (size_t)N_NODES * (N_NODES / 64) * sizeof(unsigned long long);
    int use_mask = (ws_size >= base_need + mask_bytes) ? 1 : 0;

    (void)hipMemsetAsync(d_ws, 0, zero_bytes, stream);
    hipLaunchKernelGGL(k_wh, dim3(N_NODES / 32), dim3(256), 0, stream, h, Ww, Wb, Wh, WhT);
    hipLaunchKernelGGL(k_s,  dim3(N_NODES / 4),  dim3(256), 0, stream, Wh, a, s, smax);
    hipLaunchKernelGGL(k_A,  dim3(N_NODES / BMR, NKB), dim3(256), 0, stream,
                       adj, WhT, s, smax, denom, y, bmask, use_mask);
    hipLaunchKernelGGL(k_B,  dim3(N_NODES / 4),  dim3(256), 0, stream,
                       bmask, adj, s, denom, smax, alpha, use_mask);
    hipLaunchKernelGGL(k_z,  dim3((N_NODES * H_DIM) / 256), dim3(256), 0, stream,
                       y, denom, z);
}